// Round 9
// baseline (203.267 us; speedup 1.0000x reference)
//
#include <hip/hip_runtime.h>
#include <stdint.h>

// B=2, S=2048, D=1024, H=16, HD=64. fp32 in/out, bf16 MFMA internally.

typedef __attribute__((ext_vector_type(8))) short short8;
typedef __attribute__((ext_vector_type(4))) float floatx4;

#define S_LEN 2048
#define D_DIM 1024
#define NH 16
#define HD 64
#define L2E 1.44269504088896340736f

__device__ __forceinline__ short f2bf(float f) {
    uint32_t u = __builtin_bit_cast(uint32_t, f);
    uint32_t r = u + 0x7fffu + ((u >> 16) & 1u);   // RNE
    return (short)(r >> 16);
}
__device__ __forceinline__ uint32_t pack2(float a, float b) {
#if __has_builtin(__builtin_amdgcn_cvt_pk_bf16_f32)
    auto v = __builtin_amdgcn_cvt_pk_bf16_f32(a, b);
    uint32_t r; __builtin_memcpy(&r, &v, sizeof(r)); return r;
#else
    return (uint32_t)(uint16_t)f2bf(a) | ((uint32_t)(uint16_t)f2bf(b) << 16);
#endif
}
__device__ __forceinline__ void gll16(const void* g, void* l) {
    __builtin_amdgcn_global_load_lds(
        (const __attribute__((address_space(1))) void*)g,
        (__attribute__((address_space(3))) void*)l, 16, 0, 0);
}

// -------- prep: cast X (blocks 0..4095) + transpose/cast weights (4096..8191) --------
// Block 0 additionally zeroes the attn task counter.
__global__ __launch_bounds__(256) void prep_kernel(const float* __restrict__ X,
                                                   const float* __restrict__ Wq,
                                                   const float* __restrict__ Wk,
                                                   const float* __restrict__ Wv,
                                                   const float* __restrict__ Wo,
                                                   short* __restrict__ Xb,
                                                   short* __restrict__ WqkvT,
                                                   short* __restrict__ WoT,
                                                   int* __restrict__ ctr) {
    const int b = blockIdx.x, tid = threadIdx.x;
    if (b < 4096) {
        if (b == 0 && tid == 0) ctr[0] = 0;
        const int i = b * 256 + tid;
        const float4 v = *(const float4*)(X + (size_t)i * 4);
        uint2 o;
        o.x = pack2(v.x, v.y);
        o.y = pack2(v.z, v.w);
        *(uint2*)(Xb + (size_t)i * 4) = o;
    } else {
        const int b2 = b - 4096;
        const int z = b2 >> 10, w = b2 & 1023;
        const float* W = (z == 0) ? Wq : (z == 1) ? Wk : (z == 2) ? Wv : Wo;
        short* WT = (z < 3) ? (WqkvT + (size_t)z * 1024 * 1024) : WoT;
        __shared__ float tile[32][33];
        const int bx = (w & 31) * 32;
        const int by = (w >> 5) * 32;
        const int tx = tid & 31, ty = tid >> 5;      // 32 x 8
        for (int i = 0; i < 32; i += 8)
            tile[ty + i][tx] = W[(size_t)(bx + ty + i) * D_DIM + by + tx];
        __syncthreads();
        for (int i = 0; i < 32; i += 8)
            WT[(size_t)(by + ty + i) * D_DIM + bx + tx] = f2bf(tile[tx][ty + i]);
    }
}

// ---- fused QKV GEMM: fat wave-tiles + BK=32 double-buffered prefetch ----
__global__ __launch_bounds__(256, 3) void gemm_qkv_kernel(const short* __restrict__ Xb,
                                                          const short* __restrict__ WT,
                                                          short* __restrict__ Qb,
                                                          short* __restrict__ Kb,
                                                          short* __restrict__ Vtb) {
    __shared__ __align__(16) short smem[16384];       // 32 KB: As[2]|Bs[2]
    short (*As)[4096] = (short(*)[4096])smem;
    short (*Bs)[4096] = (short(*)[4096])(smem + 8192);
    const int m0 = blockIdx.x * 128, n0 = blockIdx.y * 128;
    const int tid = threadIdx.x, lane = tid & 63, wave = tid >> 6;
    const int ln = lane & 15, quad = lane >> 4;
    const int mw = (wave & 1) * 64, nw = (wave >> 1) * 64;
    floatx4 acc[4][4] = {};

    const int c0 = tid, c1 = 256 + tid;
    const int r0 = c0 >> 2, s0 = (c0 & 3) ^ ((r0 >> 1) & 3);
    const int r1 = c1 >> 2, s1 = (c1 & 3) ^ ((r1 >> 1) & 3);
    const short* A0 = Xb + (size_t)(m0 + r0) * D_DIM + s0 * 8;
    const short* A1 = Xb + (size_t)(m0 + r1) * D_DIM + s1 * 8;
    const short* B0 = WT + (size_t)(n0 + r0) * D_DIM + s0 * 8;
    const short* B1 = WT + (size_t)(n0 + r1) * D_DIM + s1 * 8;

#define QSTAGE(buf, kk)                                    \
    {                                                      \
        const int o = (kk) * 32;                           \
        gll16(A0 + o, &As[buf][c0 * 8]);                   \
        gll16(A1 + o, &As[buf][c1 * 8]);                   \
        gll16(B0 + o, &Bs[buf][c0 * 8]);                   \
        gll16(B1 + o, &Bs[buf][c1 * 8]);                   \
    }

    QSTAGE(0, 0);
    int cur = 0;
    for (int kk = 0; kk < 32; kk++) {
        if (kk + 1 < 32) {
            QSTAGE(cur ^ 1, kk + 1);
            asm volatile("s_waitcnt vmcnt(4)" ::: "memory");
        } else {
            asm volatile("s_waitcnt vmcnt(0)" ::: "memory");
        }
        __builtin_amdgcn_s_barrier();
        __builtin_amdgcn_sched_barrier(0);
        short8 a[4], b[4];
        for (int i = 0; i < 4; i++) {
            const int row = mw + i * 16 + ln;
            a[i] = *(const short8*)(&As[cur][row * 32 + ((quad ^ ((row >> 1) & 3)) * 8)]);
        }
        for (int j = 0; j < 4; j++) {
            const int row = nw + j * 16 + ln;
            b[j] = *(const short8*)(&Bs[cur][row * 32 + ((quad ^ ((row >> 1) & 3)) * 8)]);
        }
        __builtin_amdgcn_s_setprio(1);
        for (int i = 0; i < 4; i++)
            for (int j = 0; j < 4; j++)
                acc[i][j] = __builtin_amdgcn_mfma_f32_16x16x32_bf16(a[i], b[j], acc[i][j], 0, 0, 0);
        __builtin_amdgcn_s_setprio(0);
        __builtin_amdgcn_sched_barrier(0);
        __builtin_amdgcn_s_barrier();
        __builtin_amdgcn_sched_barrier(0);
        cur ^= 1;
    }
#undef QSTAGE

    const int nsel = n0 >> 10;              // 0:Q 1:K 2:V
    if (nsel < 2) {
        const float qs = (nsel == 0) ? L2E : 1.f;
        short* outB = (nsel == 0) ? Qb : Kb;
        for (int i = 0; i < 4; i++)
            for (int j = 0; j < 4; j++)
                for (int r = 0; r < 4; r++) {
                    const int row = m0 + mw + i * 16 + quad * 4 + r;   // token
                    const int col = (n0 & 1023) + nw + j * 16 + ln;    // feature
                    const int bb = row >> 11, s = row & (S_LEN - 1);
                    const int h = col >> 6, hd = col & (HD - 1);
                    outB[(((size_t)(bb * NH + h)) * S_LEN + s) * HD + hd] = f2bf(acc[i][j][r] * qs);
                }
    } else {
        // V: transpose through LDS, then coalesced short8 stores along s.
        for (int i = 0; i < 4; i++)
            for (int j = 0; j < 4; j++) {
                const int feat = nw + j * 16 + ln;        // 0..127
                const int tok  = mw + i * 16 + quad * 4;  // %8 in {0,4}
                const int t8 = tok >> 3, lo = tok & 7;
                uint2 u;
                u.x = pack2(acc[i][j][0], acc[i][j][1]);
                u.y = pack2(acc[i][j][2], acc[i][j][3]);
                *(uint2*)&smem[feat * 128 + ((t8 ^ (feat & 15)) * 8) + lo] = u;
            }
        __syncthreads();
        const int bb = m0 >> 11, sbase = m0 & (S_LEN - 1);
        for (int c = tid; c < 2048; c += 256) {           // 2048 short8 chunks
            const int feat = c >> 4, t8 = c & 15;
            const short8 v = *(const short8*)&smem[feat * 128 + ((t8 ^ (feat & 15)) * 8)];
            const int col = (n0 & 1023) + feat;
            const int h = col >> 6, hd = col & (HD - 1);
            const int s = sbase + t8 * 8;
            *(short8*)(Vtb + (((size_t)(bb * NH + h)) * HD + hd) * S_LEN + s) = v;
        }
    }
}

// ---- output projection: fat wave-tiles + BK=32 double-buffered prefetch ----
__global__ __launch_bounds__(256, 3) void gemm_out_kernel(const short* __restrict__ Cb,
                                                          const short* __restrict__ WoT,
                                                          float* __restrict__ out,
                                                          const float* __restrict__ bias) {
    __shared__ __align__(16) short As[2][128 * 32];   // 2 x 8 KB
    __shared__ __align__(16) short Bs[2][64 * 32];    // 2 x 4 KB
    const int m0 = blockIdx.x * 128, n0 = blockIdx.y * 64;
    const int tid = threadIdx.x, lane = tid & 63;
    const int ln = lane & 15, quad = lane >> 4;
    const int wave = tid >> 6;
    const int mw = (wave & 1) * 64, nw = (wave >> 1) * 32;

    floatx4 acc[4][2] = {};

    const int c0 = tid, c1 = 256 + tid;
    const int r0 = c0 >> 2, s0 = (c0 & 3) ^ ((r0 >> 1) & 3);
    const int r1 = c1 >> 2, s1 = (c1 & 3) ^ ((r1 >> 1) & 3);
    const short* A0 = Cb + (size_t)(m0 + r0) * D_DIM + s0 * 8;
    const short* A1 = Cb + (size_t)(m0 + r1) * D_DIM + s1 * 8;
    const short* B0 = WoT + (size_t)(n0 + r0) * D_DIM + s0 * 8;   // r0 < 64 for c0 < 256

#define OSTAGE(buf, kk)                                    \
    {                                                      \
        const int o = (kk) * 32;                           \
        gll16(A0 + o, &As[buf][c0 * 8]);                   \
        gll16(A1 + o, &As[buf][c1 * 8]);                   \
        gll16(B0 + o, &Bs[buf][c0 * 8]);                   \
    }

    OSTAGE(0, 0);
    int cur = 0;
    for (int kk = 0; kk < 32; kk++) {
        if (kk + 1 < 32) {
            OSTAGE(cur ^ 1, kk + 1);
            asm volatile("s_waitcnt vmcnt(3)" ::: "memory");
        } else {
            asm volatile("s_waitcnt vmcnt(0)" ::: "memory");
        }
        __builtin_amdgcn_s_barrier();
        __builtin_amdgcn_sched_barrier(0);
        short8 a[4], b[2];
        for (int i = 0; i < 4; i++) {
            const int row = mw + i * 16 + ln;
            a[i] = *(const short8*)(&As[cur][row * 32 + ((quad ^ ((row >> 1) & 3)) * 8)]);
        }
        for (int j = 0; j < 2; j++) {
            const int row = nw + j * 16 + ln;
            b[j] = *(const short8*)(&Bs[cur][row * 32 + ((quad ^ ((row >> 1) & 3)) * 8)]);
        }
        __builtin_amdgcn_s_setprio(1);
        for (int i = 0; i < 4; i++)
            for (int j = 0; j < 2; j++)
                acc[i][j] = __builtin_amdgcn_mfma_f32_16x16x32_bf16(a[i], b[j], acc[i][j], 0, 0, 0);
        __builtin_amdgcn_s_setprio(0);
        __builtin_amdgcn_sched_barrier(0);
        __builtin_amdgcn_s_barrier();
        __builtin_amdgcn_sched_barrier(0);
        cur ^= 1;
    }
#undef OSTAGE

    for (int i = 0; i < 4; i++)
        for (int j = 0; j < 2; j++)
            for (int r = 0; r < 4; r++) {
                const int row = m0 + mw + i * 16 + quad * 4 + r;
                const int col = n0 + nw + j * 16 + ln;
                out[(size_t)row * D_DIM + col] = acc[i][j][r] + bias[col];
            }
}

// ---------------- causal flash attention (R9: persistent blocks + dynamic queue) ----------------
// 768 persistent blocks (42 KB LDS -> 3/CU, 24 waves/CU), 512 unsplit tasks
// (bh x qt) grabbed longest-first from a global atomic counter (LPT schedule).
// Per-task loop = R6's proven 64-key dbuf pipeline (counted vmcnt + raw
// barriers). No splits -> no Opart/Lpart/combine. AtomicAdd only, NO fences
// (R5 lesson). Counter zeroed by prep_kernel earlier in the stream.
__global__ __launch_bounds__(512, 6) void attn_kernel(const short* __restrict__ Q,
                                                      const short* __restrict__ Kg,
                                                      const short* __restrict__ Vt,
                                                      short* __restrict__ ctx,
                                                      int* __restrict__ ctr) {
    __shared__ __align__(16) short Ks[2][64 * 64];    // [key][hd]   2 x 8 KB
    __shared__ __align__(16) short Vs[2][64 * 64];    // [hd][key]   2 x 8 KB
    __shared__ __align__(16) short Ps[8][640];        // per-wave [16][40] 10 KB
    __shared__ int s_task;

    const int tid = threadIdx.x, wave = tid >> 6, lane = tid & 63;
    const int ln = lane & 15, quad = lane >> 4;
    short* Pw = Ps[wave];

    // staging: 512 threads x (1 K chunk + 1 V chunk) of 16 B
    const int srow = tid >> 3, spos = tid & 7, ssrc = spos ^ (srow & 7);

    for (;;) {
        if (tid == 0) s_task = atomicAdd(ctr, 1);
        __syncthreads();
        const int t = s_task;
        if (t >= 512) return;

        const int qt = 15 - (t >> 5);                  // longest tasks first
        const int hv = t & 31;
        const int bh = (hv & 7) + 8 * ((hv >> 3) & 3); // XCD head affinity
        const int ke = 2 * (qt + 1);                   // 64-key tiles
        const int kmask0 = 2 * qt;                     // diagonal region start
        const int q0 = qt * 128;
        const int bb = bh >> 4, h = bh & 15;

        const short* qrow = Q + ((size_t)bh * S_LEN + q0 + wave * 16 + ln) * HD;
        const short8 qb0 = *(const short8*)(qrow + quad * 8);
        const short8 qb1 = *(const short8*)(qrow + 32 + quad * 8);
        const int q_abs = q0 + wave * 16 + ln;

        const size_t kbase = (size_t)bh * S_LEN * HD;
        const size_t vbase = (size_t)bh * HD * S_LEN;

        float l_part = 0.f;
        floatx4 o_acc[4] = {};

#define STAGE(buf, kt_)                                                          \
    {                                                                            \
        const int k0s = (kt_) * 64;                                              \
        gll16(Kg + kbase + (size_t)(k0s + srow) * HD + ssrc * 8,                 \
              &Ks[buf][tid * 8]);                                                \
        gll16(Vt + vbase + (size_t)srow * S_LEN + k0s + ssrc * 8,                \
              &Vs[buf][tid * 8]);                                                \
    }

        int cur = 0;
        STAGE(0, 0);
        for (int kt = 0; kt < ke; kt++) {
            if (kt + 1 < ke) {
                STAGE(cur ^ 1, kt + 1);                      // prefetch next tile
                asm volatile("s_waitcnt vmcnt(2)" ::: "memory");   // wait cur only
            } else {
                asm volatile("s_waitcnt vmcnt(0)" ::: "memory");
            }
            __builtin_amdgcn_s_barrier();                    // raw: no drain
            __builtin_amdgcn_sched_barrier(0);

            const short* Kc = Ks[cur];
            const short* Vc = Vs[cur];

            // S^T: D[m=key(nt*16+quad*4+r)][n=query(ln)], 4 tiles over 64 keys
            floatx4 sc4[4];
            __builtin_amdgcn_s_setprio(1);
            for (int nt = 0; nt < 4; nt++) {
                const int row = nt * 16 + ln;
                const short8 ak0 = *(const short8*)(Kc + row * 64 + ((quad ^ (ln & 7)) * 8));
                const short8 ak1 = *(const short8*)(Kc + row * 64 + (((4 + quad) ^ (ln & 7)) * 8));
                floatx4 z = {};
                z = __builtin_amdgcn_mfma_f32_16x16x32_bf16(ak0, qb0, z, 0, 0, 0);
                z = __builtin_amdgcn_mfma_f32_16x16x32_bf16(ak1, qb1, z, 0, 0, 0);
                sc4[nt] = z;
            }
            __builtin_amdgcn_s_setprio(0);

            if (kt >= kmask0) {  // diagonal region: mask key > query
                const int k0 = kt * 64;
                for (int nt = 0; nt < 4; nt++)
                    for (int r = 0; r < 4; r++)
                        if (k0 + nt * 16 + quad * 4 + r > q_abs) sc4[nt][r] = -1e30f;
            }

            // fixed-base softmax: p = exp2(s); accumulate l per-lane only
            float ls = 0.f;
            for (int nt = 0; nt < 4; nt++)
                for (int r = 0; r < 4; r++) {
                    const float e = exp2f(sc4[nt][r]);
                    sc4[nt][r] = e; ls += e;
                }
            l_part += ls;

            // 2 phases of 32 keys: pack P^T to wave-private LDS, read B fragment,
            // 4 PV MFMA. O^T += V^T . P^T : D[m=d][n=q]
            for (int p = 0; p < 2; p++) {
                uint2 u0, u1;
                u0.x = pack2(sc4[2 * p][0], sc4[2 * p][1]);
                u0.y = pack2(sc4[2 * p][2], sc4[2 * p][3]);
                u1.x = pack2(sc4[2 * p + 1][0], sc4[2 * p + 1][1]);
                u1.y = pack2(sc4[2 * p + 1][2], sc4[2 * p + 1][3]);
                *(uint2*)&Pw[ln * 40 + quad * 4]      = u0;
                *(uint2*)&Pw[ln * 40 + 16 + quad * 4] = u1;
                const short8 bp = *(const short8*)&Pw[ln * 40 + quad * 8];
                __builtin_amdgcn_s_setprio(1);
                for (int dt = 0; dt < 4; dt++) {
                    const int row = dt * 16 + ln;
                    const short8 av = *(const short8*)(Vc + row * 64 + (((p * 4 + quad) ^ (ln & 7)) * 8));
                    o_acc[dt] = __builtin_amdgcn_mfma_f32_16x16x32_bf16(av, bp, o_acc[dt], 0, 0, 0);
                }
                __builtin_amdgcn_s_setprio(0);
            }

            __builtin_amdgcn_sched_barrier(0);
            __builtin_amdgcn_s_barrier();    // all waves done reading cur
            __builtin_amdgcn_sched_barrier(0);
            cur ^= 1;
        }
#undef STAGE

        // reduce l across the 4 quads once
        float l_tot = l_part;
        l_tot += __shfl_xor(l_tot, 16, 64);
        l_tot += __shfl_xor(l_tot, 32, 64);

        const float rl = 1.f / l_tot;
        const int qr = lane >> 2, sg = lane & 3;
        for (int c = 0; c < 2; c++) {     // d-halves, staged through Pw
            for (int dd = 0; dd < 2; dd++) {
                const int dt = c * 2 + dd;
                uint2 u;
                u.x = pack2(o_acc[dt][0] * rl, o_acc[dt][1] * rl);
                u.y = pack2(o_acc[dt][2] * rl, o_acc[dt][3] * rl);
                *(uint2*)&Pw[ln * 40 + dd * 16 + quad * 4] = u;
            }
            const short8 v = *(const short8*)&Pw[qr * 40 + sg * 8];
            const int s = q0 + wave * 16 + qr;
            *(short8*)(ctx + ((size_t)bb * S_LEN + s) * D_DIM + h * HD + sg * 8 + c * 32) = v;
        }
        __syncthreads();   // Pw/Ks/Vs quiesce before next task's STAGE
    }
}

// ---------------- launch ----------------
extern "C" void kernel_launch(void* const* d_in, const int* in_sizes, int n_in,
                              void* d_out, int out_size, void* d_ws, size_t ws_size,
                              hipStream_t stream) {
    const float* X  = (const float*)d_in[0];
    const float* Wq = (const float*)d_in[1];
    const float* Wk = (const float*)d_in[2];
    const float* Wv = (const float*)d_in[3];
    const float* Wo = (const float*)d_in[4];
    const float* bo = (const float*)d_in[5];
    float* out = (float*)d_out;

    char* ws = (char*)d_ws;
    const size_t MB = 1024 * 1024;
    short* Xb     = (short*)(ws);                 //  0- 8 MB
    short* WqkvT  = (short*)(ws + 8  * MB);       //  8-14 MB
    short* Qb     = (short*)(ws + 16 * MB);       // 16-24 MB [B,H,S,HD], pre-scaled by log2e
    short* Kb     = (short*)(ws + 24 * MB);       // 24-32 MB [B,H,S,HD]
    short* Vtb    = (short*)(ws + 32 * MB);       // 32-40 MB [B,H,HD,S]
    short* ctxb   = (short*)(ws + 40 * MB);       // 40-48 MB [4096][1024]
    short* WoT    = (short*)(ws + 48 * MB);       // 48-50 MB
    int*   ctr    = (int*)(ws + 51 * MB);         // 51 MB: attn task counter

    prep_kernel<<<8192, 256, 0, stream>>>(X, Wq, Wk, Wv, Wo, Xb, WqkvT, WoT, ctr);

    dim3 gq(32, 24);   // M=4096/128, N=3072/128
    gemm_qkv_kernel<<<gq, 256, 0, stream>>>(Xb, WqkvT, Qb, Kb, Vtb);

    attn_kernel<<<768, 512, 0, stream>>>(Qb, Kb, Vtb, ctxb, ctr);

    dim3 go(32, 16);   // M=4096/128, N=1024/64 -> 512 blocks
    gemm_out_kernel<<<go, 256, 0, stream>>>(ctxb, WoT, out, bo);
}

// Round 10
// 176.391 us; speedup vs baseline: 1.1524x; 1.1524x over previous
//
#include <hip/hip_runtime.h>
#include <stdint.h>

// B=2, S=2048, D=1024, H=16, HD=64. fp32 in/out, bf16 MFMA internally.

typedef __attribute__((ext_vector_type(8))) short short8;
typedef __attribute__((ext_vector_type(4))) float floatx4;

#define S_LEN 2048
#define D_DIM 1024
#define NH 16
#define HD 64
#define L2E 1.44269504088896340736f

__device__ __forceinline__ short f2bf(float f) {
    uint32_t u = __builtin_bit_cast(uint32_t, f);
    uint32_t r = u + 0x7fffu + ((u >> 16) & 1u);   // RNE
    return (short)(r >> 16);
}
__device__ __forceinline__ uint32_t pack2(float a, float b) {
#if __has_builtin(__builtin_amdgcn_cvt_pk_bf16_f32)
    auto v = __builtin_amdgcn_cvt_pk_bf16_f32(a, b);
    uint32_t r; __builtin_memcpy(&r, &v, sizeof(r)); return r;
#else
    return (uint32_t)(uint16_t)f2bf(a) | ((uint32_t)(uint16_t)f2bf(b) << 16);
#endif
}
__device__ __forceinline__ void gll16(const void* g, void* l) {
    __builtin_amdgcn_global_load_lds(
        (const __attribute__((address_space(1))) void*)g,
        (__attribute__((address_space(3))) void*)l, 16, 0, 0);
}

// -------- prep: cast X (blocks 0..4095) + transpose/cast weights (4096..8191) --------
__global__ __launch_bounds__(256) void prep_kernel(const float* __restrict__ X,
                                                   const float* __restrict__ Wq,
                                                   const float* __restrict__ Wk,
                                                   const float* __restrict__ Wv,
                                                   const float* __restrict__ Wo,
                                                   short* __restrict__ Xb,
                                                   short* __restrict__ WqkvT,
                                                   short* __restrict__ WoT) {
    const int b = blockIdx.x, tid = threadIdx.x;
    if (b < 4096) {
        const int i = b * 256 + tid;
        const float4 v = *(const float4*)(X + (size_t)i * 4);
        uint2 o;
        o.x = pack2(v.x, v.y);
        o.y = pack2(v.z, v.w);
        *(uint2*)(Xb + (size_t)i * 4) = o;
    } else {
        const int b2 = b - 4096;
        const int z = b2 >> 10, w = b2 & 1023;
        const float* W = (z == 0) ? Wq : (z == 1) ? Wk : (z == 2) ? Wv : Wo;
        short* WT = (z < 3) ? (WqkvT + (size_t)z * 1024 * 1024) : WoT;
        __shared__ float tile[32][33];
        const int bx = (w & 31) * 32;
        const int by = (w >> 5) * 32;
        const int tx = tid & 31, ty = tid >> 5;      // 32 x 8
        for (int i = 0; i < 32; i += 8)
            tile[ty + i][tx] = W[(size_t)(bx + ty + i) * D_DIM + by + tx];
        __syncthreads();
        for (int i = 0; i < 32; i += 8)
            WT[(size_t)(by + ty + i) * D_DIM + bx + tx] = f2bf(tile[tx][ty + i]);
    }
}

// ---- fused QKV GEMM: fat wave-tiles + BK=32 dbuf, SINGLE barrier per K-step ----
// Pre-step barrier (after own-wave vmcnt(0) on stage(k)) certifies both
// "stage(k) landed" and "all waves done reading k-1's buffer", so stage(k+1)
// issues right after it and overlaps the whole compute phase.
__global__ __launch_bounds__(256, 3) void gemm_qkv_kernel(const short* __restrict__ Xb,
                                                          const short* __restrict__ WT,
                                                          short* __restrict__ Qb,
                                                          short* __restrict__ Kb,
                                                          short* __restrict__ Vtb) {
    __shared__ __align__(16) short smem[16384];       // 32 KB: As[2]|Bs[2]
    short (*As)[4096] = (short(*)[4096])smem;
    short (*Bs)[4096] = (short(*)[4096])(smem + 8192);
    const int m0 = blockIdx.x * 128, n0 = blockIdx.y * 128;
    const int tid = threadIdx.x, lane = tid & 63, wave = tid >> 6;
    const int ln = lane & 15, quad = lane >> 4;
    const int mw = (wave & 1) * 64, nw = (wave >> 1) * 64;
    floatx4 acc[4][4] = {};

    const int c0 = tid, c1 = 256 + tid;
    const int r0 = c0 >> 2, s0 = (c0 & 3) ^ ((r0 >> 1) & 3);
    const int r1 = c1 >> 2, s1 = (c1 & 3) ^ ((r1 >> 1) & 3);
    const short* A0 = Xb + (size_t)(m0 + r0) * D_DIM + s0 * 8;
    const short* A1 = Xb + (size_t)(m0 + r1) * D_DIM + s1 * 8;
    const short* B0 = WT + (size_t)(n0 + r0) * D_DIM + s0 * 8;
    const short* B1 = WT + (size_t)(n0 + r1) * D_DIM + s1 * 8;

#define QSTAGE(buf, kk)                                    \
    {                                                      \
        const int o = (kk) * 32;                           \
        gll16(A0 + o, &As[buf][c0 * 8]);                   \
        gll16(A1 + o, &As[buf][c1 * 8]);                   \
        gll16(B0 + o, &Bs[buf][c0 * 8]);                   \
        gll16(B1 + o, &Bs[buf][c1 * 8]);                   \
    }

    QSTAGE(0, 0);
    int cur = 0;
    for (int kk = 0; kk < 32; kk++) {
        asm volatile("s_waitcnt vmcnt(0)" ::: "memory");   // own stage(kk) done
        __builtin_amdgcn_s_barrier();                      // all stages done +
        __builtin_amdgcn_sched_barrier(0);                 // all kk-1 reads done
        if (kk + 1 < 32) QSTAGE(cur ^ 1, kk + 1);          // overlap with compute
        short8 a[4], b[4];
        for (int i = 0; i < 4; i++) {
            const int row = mw + i * 16 + ln;
            a[i] = *(const short8*)(&As[cur][row * 32 + ((quad ^ ((row >> 1) & 3)) * 8)]);
        }
        for (int j = 0; j < 4; j++) {
            const int row = nw + j * 16 + ln;
            b[j] = *(const short8*)(&Bs[cur][row * 32 + ((quad ^ ((row >> 1) & 3)) * 8)]);
        }
        __builtin_amdgcn_s_setprio(1);
        for (int i = 0; i < 4; i++)
            for (int j = 0; j < 4; j++)
                acc[i][j] = __builtin_amdgcn_mfma_f32_16x16x32_bf16(a[i], b[j], acc[i][j], 0, 0, 0);
        __builtin_amdgcn_s_setprio(0);
        cur ^= 1;
    }
#undef QSTAGE

    const int nsel = n0 >> 10;              // 0:Q 1:K 2:V
    if (nsel < 2) {
        const float qs = (nsel == 0) ? L2E : 1.f;
        short* outB = (nsel == 0) ? Qb : Kb;
        for (int i = 0; i < 4; i++)
            for (int j = 0; j < 4; j++)
                for (int r = 0; r < 4; r++) {
                    const int row = m0 + mw + i * 16 + quad * 4 + r;   // token
                    const int col = (n0 & 1023) + nw + j * 16 + ln;    // feature
                    const int bb = row >> 11, s = row & (S_LEN - 1);
                    const int h = col >> 6, hd = col & (HD - 1);
                    outB[(((size_t)(bb * NH + h)) * S_LEN + s) * HD + hd] = f2bf(acc[i][j][r] * qs);
                }
    } else {
        // V: transpose through LDS, then coalesced short8 stores along s.
        __syncthreads();   // laggard waves may still read As/Bs of last K-step
        for (int i = 0; i < 4; i++)
            for (int j = 0; j < 4; j++) {
                const int feat = nw + j * 16 + ln;        // 0..127
                const int tok  = mw + i * 16 + quad * 4;  // %8 in {0,4}
                const int t8 = tok >> 3, lo = tok & 7;
                uint2 u;
                u.x = pack2(acc[i][j][0], acc[i][j][1]);
                u.y = pack2(acc[i][j][2], acc[i][j][3]);
                *(uint2*)&smem[feat * 128 + ((t8 ^ (feat & 15)) * 8) + lo] = u;
            }
        __syncthreads();
        const int bb = m0 >> 11, sbase = m0 & (S_LEN - 1);
        for (int c = tid; c < 2048; c += 256) {           // 2048 short8 chunks
            const int feat = c >> 4, t8 = c & 15;
            const short8 v = *(const short8*)&smem[feat * 128 + ((t8 ^ (feat & 15)) * 8)];
            const int col = (n0 & 1023) + feat;
            const int h = col >> 6, hd = col & (HD - 1);
            const int s = sbase + t8 * 8;
            *(short8*)(Vtb + (((size_t)(bb * NH + h)) * HD + hd) * S_LEN + s) = v;
        }
    }
}

// ---- output projection: fat wave-tiles + BK=32 dbuf, single barrier per K-step ----
__global__ __launch_bounds__(256, 3) void gemm_out_kernel(const short* __restrict__ Cb,
                                                          const short* __restrict__ WoT,
                                                          float* __restrict__ out,
                                                          const float* __restrict__ bias) {
    __shared__ __align__(16) short As[2][128 * 32];   // 2 x 8 KB
    __shared__ __align__(16) short Bs[2][64 * 32];    // 2 x 4 KB
    const int m0 = blockIdx.x * 128, n0 = blockIdx.y * 64;
    const int tid = threadIdx.x, lane = tid & 63;
    const int ln = lane & 15, quad = lane >> 4;
    const int wave = tid >> 6;
    const int mw = (wave & 1) * 64, nw = (wave >> 1) * 32;

    floatx4 acc[4][2] = {};

    const int c0 = tid, c1 = 256 + tid;
    const int r0 = c0 >> 2, s0 = (c0 & 3) ^ ((r0 >> 1) & 3);
    const int r1 = c1 >> 2, s1 = (c1 & 3) ^ ((r1 >> 1) & 3);
    const short* A0 = Cb + (size_t)(m0 + r0) * D_DIM + s0 * 8;
    const short* A1 = Cb + (size_t)(m0 + r1) * D_DIM + s1 * 8;
    const short* B0 = WoT + (size_t)(n0 + r0) * D_DIM + s0 * 8;   // r0 < 64 for c0 < 256

#define OSTAGE(buf, kk)                                    \
    {                                                      \
        const int o = (kk) * 32;                           \
        gll16(A0 + o, &As[buf][c0 * 8]);                   \
        gll16(A1 + o, &As[buf][c1 * 8]);                   \
        gll16(B0 + o, &Bs[buf][c0 * 8]);                   \
    }

    OSTAGE(0, 0);
    int cur = 0;
    for (int kk = 0; kk < 32; kk++) {
        asm volatile("s_waitcnt vmcnt(0)" ::: "memory");   // own stage(kk) done
        __builtin_amdgcn_s_barrier();
        __builtin_amdgcn_sched_barrier(0);
        if (kk + 1 < 32) OSTAGE(cur ^ 1, kk + 1);
        short8 a[4], b[2];
        for (int i = 0; i < 4; i++) {
            const int row = mw + i * 16 + ln;
            a[i] = *(const short8*)(&As[cur][row * 32 + ((quad ^ ((row >> 1) & 3)) * 8)]);
        }
        for (int j = 0; j < 2; j++) {
            const int row = nw + j * 16 + ln;
            b[j] = *(const short8*)(&Bs[cur][row * 32 + ((quad ^ ((row >> 1) & 3)) * 8)]);
        }
        __builtin_amdgcn_s_setprio(1);
        for (int i = 0; i < 4; i++)
            for (int j = 0; j < 2; j++)
                acc[i][j] = __builtin_amdgcn_mfma_f32_16x16x32_bf16(a[i], b[j], acc[i][j], 0, 0, 0);
        __builtin_amdgcn_s_setprio(0);
        cur ^= 1;
    }
#undef OSTAGE

    for (int i = 0; i < 4; i++)
        for (int j = 0; j < 2; j++)
            for (int r = 0; r < 4; r++) {
                const int row = m0 + mw + i * 16 + quad * 4 + r;
                const int col = n0 + nw + j * 16 + ln;
                out[(size_t)row * D_DIM + col] = acc[i][j][r] + bias[col];
            }
}

// ---------------- causal flash attention (R10: R8 + single barrier per tile) ----------------
// 512 blocks, 512 threads, static (qt, 15-qt) CU-pairing (17 tiles/CU, same-bh
// L2 locality). 128-key dbuf tiles. ONE barrier + ONE vmcnt per tile: the
// pre-tile barrier (after own-wave vmcnt(0) on stage(t)) certifies stage(t)
// complete AND all waves done reading t-1's buffer -> stage(t+1) issues right
// after and overlaps the whole QK/SM/PV phase; waves drift freely within the
// tile (no post-PV convoy).
__global__ __launch_bounds__(512, 4) void attn_kernel(const short* __restrict__ Q,
                                                      const short* __restrict__ Kg,
                                                      const short* __restrict__ Vt,
                                                      short* __restrict__ ctx) {
    __shared__ __align__(16) short Ks[2][128 * 64];   // [key][hd]  2 x 16 KB
    __shared__ __align__(16) short Vs[2][64 * 128];   // [hd][key]  2 x 16 KB
    __shared__ __align__(16) short Ps[8][640];        // per-wave [16][40] 10 KB

    const int tid = threadIdx.x, wave = tid >> 6, lane = tid & 63;
    const int ln = lane & 15, quad = lane >> 4;

    const int id = blockIdx.x;            // 0..511
    const int hv = (id < 256) ? id : id - 256;
    const int bh = (hv & 7) + 8 * ((hv >> 3) & 3);    // XCD head affinity
    const int qt = (id < 256) ? 8 + (hv >> 5) : 7 - (hv >> 5);
    const int ke = qt + 1;                // 128-key tiles
    const int q0 = qt * 128;
    const int bb = bh >> 4, h = bh & 15;
    short* Pw = Ps[wave];

    const short* qrow = Q + ((size_t)bh * S_LEN + q0 + wave * 16 + ln) * HD;
    const short8 qb0 = *(const short8*)(qrow + quad * 8);
    const short8 qb1 = *(const short8*)(qrow + 32 + quad * 8);
    const int q_abs = q0 + wave * 16 + ln;

    // staging: 512 threads x (2 K chunks + 2 V chunks) of 16 B per tile
    const size_t kbase = (size_t)bh * S_LEN * HD;
    const size_t vbase = (size_t)bh * HD * S_LEN;
    const int ck0 = tid, ck1 = tid + 512;             // K chunks (row stride 8)
    const int kr0 = ck0 >> 3, ks0 = (ck0 & 7) ^ (kr0 & 7);
    const int kr1 = ck1 >> 3, ks1 = (ck1 & 7) ^ (kr1 & 7);
    const int vr0 = ck0 >> 4, vs0 = (ck0 & 15) ^ (vr0 & 15);   // V chunks (row stride 16)
    const int vr1 = ck1 >> 4, vs1 = (ck1 & 15) ^ (vr1 & 15);

    float l_part = 0.f;
    floatx4 o_acc[4] = {};

#define STAGE(buf, kt_)                                                           \
    {                                                                             \
        const int k0s = (kt_) * 128;                                              \
        gll16(Kg + kbase + (size_t)(k0s + kr0) * HD + ks0 * 8, &Ks[buf][ck0 * 8]);\
        gll16(Kg + kbase + (size_t)(k0s + kr1) * HD + ks1 * 8, &Ks[buf][ck1 * 8]);\
        gll16(Vt + vbase + (size_t)vr0 * S_LEN + k0s + vs0 * 8, &Vs[buf][ck0 * 8]);\
        gll16(Vt + vbase + (size_t)vr1 * S_LEN + k0s + vs1 * 8, &Vs[buf][ck1 * 8]);\
    }

    int cur = 0;
    STAGE(0, 0);
    for (int kt = 0; kt < ke; kt++) {
        asm volatile("s_waitcnt vmcnt(0)" ::: "memory");   // own stage(kt) done
        __builtin_amdgcn_s_barrier();                      // all stages landed +
        __builtin_amdgcn_sched_barrier(0);                 // all kt-1 reads done
        if (kt + 1 < ke) STAGE(cur ^ 1, kt + 1);           // overlap with compute

        const short* Kc = Ks[cur];
        const short* Vc = Vs[cur];

        // S^T: D[m=key(nt*16+quad*4+r)][n=query(ln)], 8 tiles over 128 keys
        floatx4 sc[8];
        __builtin_amdgcn_s_setprio(1);
        for (int nt = 0; nt < 8; nt++) {
            const int row = nt * 16 + ln;
            const short8 ak0 = *(const short8*)(Kc + row * 64 + ((quad ^ (ln & 7)) * 8));
            const short8 ak1 = *(const short8*)(Kc + row * 64 + (((4 + quad) ^ (ln & 7)) * 8));
            floatx4 z = {};
            z = __builtin_amdgcn_mfma_f32_16x16x32_bf16(ak0, qb0, z, 0, 0, 0);
            z = __builtin_amdgcn_mfma_f32_16x16x32_bf16(ak1, qb1, z, 0, 0, 0);
            sc[nt] = z;
        }
        __builtin_amdgcn_s_setprio(0);

        if (kt == qt) {  // diagonal tile: mask key > query
            const int k0 = kt * 128;
            for (int nt = 0; nt < 8; nt++)
                for (int r = 0; r < 4; r++)
                    if (k0 + nt * 16 + quad * 4 + r > q_abs) sc[nt][r] = -1e30f;
        }

        // fixed-base softmax: p = exp2(s); accumulate l per-lane only
        float ls = 0.f;
        for (int nt = 0; nt < 8; nt++)
            for (int r = 0; r < 4; r++) {
                const float e = exp2f(sc[nt][r]);
                sc[nt][r] = e; ls += e;
            }
        l_part += ls;

        // 4 phases of 32 keys: pack P^T to wave-private LDS, read B fragment,
        // 4 PV MFMA. O^T += V^T . P^T : D[m=d][n=q]
        for (int p = 0; p < 4; p++) {
            uint2 u0, u1;
            u0.x = pack2(sc[2 * p][0], sc[2 * p][1]);
            u0.y = pack2(sc[2 * p][2], sc[2 * p][3]);
            u1.x = pack2(sc[2 * p + 1][0], sc[2 * p + 1][1]);
            u1.y = pack2(sc[2 * p + 1][2], sc[2 * p + 1][3]);
            *(uint2*)&Pw[ln * 40 + quad * 4]      = u0;
            *(uint2*)&Pw[ln * 40 + 16 + quad * 4] = u1;
            const short8 bp = *(const short8*)&Pw[ln * 40 + quad * 8];
            __builtin_amdgcn_s_setprio(1);
            for (int dt = 0; dt < 4; dt++) {
                const int row = dt * 16 + ln;
                const short8 av = *(const short8*)(Vc + row * 128 + (((p * 4 + quad) ^ (ln & 15)) * 8));
                o_acc[dt] = __builtin_amdgcn_mfma_f32_16x16x32_bf16(av, bp, o_acc[dt], 0, 0, 0);
            }
            __builtin_amdgcn_s_setprio(0);
        }

        cur ^= 1;     // next tile's barrier certifies these reads are done
    }
#undef STAGE

    // reduce l across the 4 quads once
    float l_tot = l_part;
    l_tot += __shfl_xor(l_tot, 16, 64);
    l_tot += __shfl_xor(l_tot, 32, 64);

    const float rl = 1.f / l_tot;
    const int qr = lane >> 2, sg = lane & 3;
    for (int c = 0; c < 2; c++) {     // d-halves, staged through wave-private Pw
        for (int dd = 0; dd < 2; dd++) {
            const int dt = c * 2 + dd;
            uint2 u;
            u.x = pack2(o_acc[dt][0] * rl, o_acc[dt][1] * rl);
            u.y = pack2(o_acc[dt][2] * rl, o_acc[dt][3] * rl);
            *(uint2*)&Pw[ln * 40 + dd * 16 + quad * 4] = u;
        }
        const short8 v = *(const short8*)&Pw[qr * 40 + sg * 8];
        const int s = q0 + wave * 16 + qr;
        *(short8*)(ctx + ((size_t)bb * S_LEN + s) * D_DIM + h * HD + sg * 8 + c * 32) = v;
    }
}

// ---------------- launch ----------------
extern "C" void kernel_launch(void* const* d_in, const int* in_sizes, int n_in,
                              void* d_out, int out_size, void* d_ws, size_t ws_size,
                              hipStream_t stream) {
    const float* X  = (const float*)d_in[0];
    const float* Wq = (const float*)d_in[1];
    const float* Wk = (const float*)d_in[2];
    const float* Wv = (const float*)d_in[3];
    const float* Wo = (const float*)d_in[4];
    const float* bo = (const float*)d_in[5];
    float* out = (float*)d_out;

    char* ws = (char*)d_ws;
    const size_t MB = 1024 * 1024;
    short* Xb     = (short*)(ws);                 //  0- 8 MB
    short* WqkvT  = (short*)(ws + 8  * MB);       //  8-14 MB
    short* Qb     = (short*)(ws + 16 * MB);       // 16-24 MB [B,H,S,HD], pre-scaled by log2e
    short* Kb     = (short*)(ws + 24 * MB);       // 24-32 MB [B,H,S,HD]
    short* Vtb    = (short*)(ws + 32 * MB);       // 32-40 MB [B,H,HD,S]
    short* ctxb   = (short*)(ws + 40 * MB);       // 40-48 MB [4096][1024]
    short* WoT    = (short*)(ws + 48 * MB);       // 48-50 MB

    prep_kernel<<<8192, 256, 0, stream>>>(X, Wq, Wk, Wv, Wo, Xb, WqkvT, WoT);

    dim3 gq(32, 24);   // M=4096/128, N=3072/128
    gemm_qkv_kernel<<<gq, 256, 0, stream>>>(Xb, WqkvT, Qb, Kb, Vtb);

    attn_kernel<<<512, 512, 0, stream>>>(Qb, Kb, Vtb, ctxb);

    dim3 go(32, 16);   // M=4096/128, N=1024/64 -> 512 blocks
    gemm_out_kernel<<<go, 256, 0, stream>>>(ctxb, WoT, out, bo);
}